// Round 6
// baseline (137.517 us; speedup 1.0000x reference)
//
#include <hip/hip_runtime.h>
#include <hip/hip_bf16.h>

#define B_ 16
#define H_ 128
#define L_ 4096
#define N_ 64
#define DT_ 0.01f

typedef __bf16 bf16;
typedef __bf16 bf16x8 __attribute__((ext_vector_type(8)));
typedef __bf16 bf16x4 __attribute__((ext_vector_type(4)));
typedef __bf16 bf16x2 __attribute__((ext_vector_type(2)));
typedef float f32x4 __attribute__((ext_vector_type(4)));

#define USWZ(c, k) ((c) * 64 + (((((k) >> 4) ^ ((c) & 3)) << 4) | ((k) & 15)))
#define SSWZ(c, k) ((c) * 128 + (((((k) >> 4) ^ ((c) & 7)) << 4) | ((k) & 15)))

// ---------------------------------------------------------------- k_ssm3 ----
// BYTE-IDENTICAL to the r4 PASS build (130.5 us session anchor). 512x512,
// 2 blocks/CU, r0-proven serial wave-0 scan overlapped with waves 1-7 T@U,
// u prefetch after the MFMA-1 barrier. Do NOT touch in this round: r6 is a
// single-variable test of k_mlp-32 (the one unindicted piece of r5's bundle).
__global__ __launch_bounds__(512, 4) void k_ssm3(
        const float* __restrict__ u,
        const float* __restrict__ lre, const float* __restrict__ lim,
        const float* __restrict__ wre, const float* __restrict__ wim,
        const float* __restrict__ dv,
        const float* __restrict__ w1, const float* __restrict__ w2,
        bf16* __restrict__ w1b, bf16* __restrict__ w2b,
        bf16* __restrict__ ybf) {
    alignas(16) __shared__ char smem[68352];
    bf16*  Ubf  = (bf16*)smem;                    //  8192 B
    float* Ctr  = (float*)(smem + 8192);          // 33280 B fp32 [row][c] stride 65 (aliased Yb)
    bf16*  Sbf  = (bf16*)(smem + 41472);          // 16384 B
    bf16*  Tm   = (bf16*)(smem + 57856);          //  9216 B
    float* lamS = (float*)(smem + 67072);         //  1024 B: [lr|li|wr|wi][64] (lr,li pre-scaled)
    float* taps = (float*)(smem + 68096);         //   256 B

    const int tid  = threadIdx.x;
    const int lane = tid & 63, wv = tid >> 6;     // wv in [0,8)
    const int cl   = lane & 15, q = lane >> 4;
    const int bId  = blockIdx.x;
    const int h    = bId & 127;
    const int bg   = bId >> 7;                    // [0,4)
    const int c0   = tid >> 3, j0 = (tid & 7) << 3;

    // ---- issue it=0 u loads FIRST: latency hides under transcendental setup
    const float4* ps0 = (const float4*)(u + (size_t)((bg * 4) * 128 + h) * L_ + c0 * 64 + j0);
    const float4 f0 = ps0[0], f1 = ps0[1];

    // ---- weight cast + lambda/W staging ----
    if (tid < 64) {
        if (bId < 256) w1b[bId * 64 + tid] = (bf16)w1[bId * 64 + tid];
        else           w2b[(bId - 256) * 64 + tid] = (bf16)w2[(bId - 256) * 64 + tid];
        lamS[tid]       = lre[h * 64 + tid] * DT_;
        lamS[64 + tid]  = lim[h * 64 + tid] * DT_;
        lamS[128 + tid] = wre[h * 64 + tid];
        lamS[192 + tid] = wim[h * 64 + tid];
    }
    __syncthreads();

    // ---- P fragments (MFMA-1 A-op) in regs: row = wv*16+cl ----
    bf16x8 pA0, pA1;
    {
        const int row = wv * 16 + cl;
        const int n = row & 63;
        const bool isIm = row >= 64;
        const float lr = lamS[n], li = lamS[64 + n];
        #pragma unroll
        for (int jj = 0; jj < 8; ++jj) {
            const float p0 = (float)(63 - (q * 8 + jj));
            const float e0 = __expf(p0 * lr);
            pA0[jj] = (bf16)(isIm ? e0 * __sinf(p0 * li) : e0 * __cosf(p0 * li));
            const float p1 = (float)(63 - (32 + q * 8 + jj));
            const float e1 = __expf(p1 * lr);
            pA1[jj] = (bf16)(isIm ? e1 * __sinf(p1 * li) : e1 * __cosf(p1 * li));
        }
    }
    // ---- Q fragments (MFMA-2 A-op) in regs: dlt = (wv>>1)*16+cl ----
    bf16x8 qA[4];
    {
        const float fd = (float)((wv >> 1) * 16 + cl + 1);   // dlt+1
        #pragma unroll
        for (int ks = 0; ks < 4; ++ks) {
            #pragma unroll
            for (int nn = 0; nn < 4; ++nn) {
                const int n = ks * 16 + q * 4 + nn;          // n = k>>1
                const float lr = lamS[n], li = lamS[64 + n];
                const float wr = lamS[128 + n], wi = lamS[192 + n];
                const float e  = __expf(fd * lr);
                const float cr = e * __cosf(fd * li), ci = e * __sinf(fd * li);
                qA[ks][2 * nn]     = (bf16)(wr * cr - wi * ci);
                qA[ks][2 * nn + 1] = (bf16)(-(wr * ci + wi * cr));
            }
        }
    }
    // ---- A^64 for the scan (lane = mode n) ----
    float a64r, a64i;
    {
        const float lr = lamS[lane], li = lamS[64 + lane];
        const float e = __expf(64.f * lr);
        a64r = e * __cosf(64.f * li);
        a64i = e * __sinf(64.f * li);
    }
    // ---- taps[dlt] = sum_n Re(W_n A_n^dlt): wave wv does dlt = wv*8+i ----
    {
        const float lr = lamS[lane], li = lamS[64 + lane];
        const float wr = lamS[128 + lane], wi = lamS[192 + lane];
        #pragma unroll
        for (int i = 0; i < 8; ++i) {
            const int dlt = wv * 8 + i;
            const float fd = (float)dlt;
            const float e = __expf(fd * lr);
            float t = wr * e * __cosf(fd * li) - wi * e * __sinf(fd * li);
            #pragma unroll
            for (int d = 1; d < 64; d <<= 1) t += __shfl_xor(t, d, 64);
            if (lane == 0) taps[dlt] = t;
        }
    }
    // ---- stage it=0 u into Ubf (loads already in flight) ----
    {
        bf16x8 t;
        t[0] = (bf16)f0.x; t[1] = (bf16)f0.y; t[2] = (bf16)f0.z; t[3] = (bf16)f0.w;
        t[4] = (bf16)f1.x; t[5] = (bf16)f1.y; t[6] = (bf16)f1.z; t[7] = (bf16)f1.w;
        *(bf16x8*)(&Ubf[USWZ(c0, j0)]) = t;
    }
    __syncthreads();

    // ---- Toeplitz Tm[dlt][j] = taps[dlt-j] (+d_h on diag) ----
    {
        const int dlt = tid >> 3, jj0 = (tid & 7) << 3;
        const float dh = dv[h];
        bf16x8 t;
        #pragma unroll
        for (int e = 0; e < 8; ++e) {
            const int j = jj0 + e;
            float v = (j <= dlt) ? taps[dlt - j] : 0.f;
            if (j == dlt) v += dh;
            t[e] = (bf16)v;
        }
        *(bf16x8*)(&Tm[dlt * 72 + jj0]) = t;
    }

    // ---- 4 batches per block ----
    const int mt = wv >> 1, nt0 = (wv & 1) * 2;
    float4 pf0 = {0.f, 0.f, 0.f, 0.f}, pf1 = {0.f, 0.f, 0.f, 0.f};
    for (int it = 0; it < 4; ++it) {
        const int bh = (bg * 4 + it) * 128 + h;

        // MFMA-1: Ctr[row][c] = P @ U (fp32), wave wv owns rows [16wv,16wv+16)
        {
            f32x4 acc[4];
            #pragma unroll
            for (int nt = 0; nt < 4; ++nt) acc[nt] = (f32x4){0.f, 0.f, 0.f, 0.f};
            #pragma unroll
            for (int nt = 0; nt < 4; ++nt) {
                const int c = nt * 16 + cl;
                const bf16x8 b0 = *(const bf16x8*)(&Ubf[USWZ(c, q * 8)]);
                acc[nt] = __builtin_amdgcn_mfma_f32_16x16x32_bf16(pA0, b0, acc[nt], 0, 0, 0);
                const bf16x8 bq = *(const bf16x8*)(&Ubf[USWZ(c, 32 + q * 8)]);
                acc[nt] = __builtin_amdgcn_mfma_f32_16x16x32_bf16(pA1, bq, acc[nt], 0, 0, 0);
            }
            #pragma unroll
            for (int nt = 0; nt < 4; ++nt)
                #pragma unroll
                for (int r = 0; r < 4; ++r)
                    Ctr[(wv * 16 + q * 4 + r) * 65 + nt * 16 + cl] = acc[nt][r];
        }
        __syncthreads();

        // issue u prefetch for it+1 here: outside MFMA-1's register-pressure
        // peak; the scan/T@U phase below hides the HBM latency
        if (it < 3) {
            const float4* ps = (const float4*)(u + (size_t)((bg * 4 + it + 1) * 128 + h) * L_
                                               + c0 * 64 + j0);
            pf0 = ps[0]; pf1 = ps[1];
        }

        // OVERLAPPED PHASE: wave 0 scans; waves 1-7 do the S-independent T@U
        f32x4 acc2[2];
        acc2[0] = (f32x4){0.f, 0.f, 0.f, 0.f};
        acc2[1] = (f32x4){0.f, 0.f, 0.f, 0.f};
        if (wv == 0) {
            float sr = 0.f, si = 0.f;
            #pragma unroll 8
            for (int c = 0; c < 64; ++c) {
                bf16* sp = &Sbf[SSWZ(c, 2 * lane)];
                sp[0] = (bf16)sr;
                sp[1] = (bf16)si;
                const float cr = Ctr[lane * 65 + c];
                const float ci = Ctr[(64 + lane) * 65 + c];
                const float nr = fmaf(a64r, sr, fmaf(-a64i, si, cr));
                const float ni = fmaf(a64r, si, fmaf(a64i, sr, ci));
                sr = nr; si = ni;
            }
        } else {
            #pragma unroll
            for (int ks = 0; ks < 2; ++ks) {
                const int k0 = ks * 32 + q * 8;
                const bf16x8 a = *(const bf16x8*)(&Tm[(mt * 16 + cl) * 72 + k0]);
                #pragma unroll
                for (int j = 0; j < 2; ++j) {
                    const int c = (nt0 + j) * 16 + cl;
                    const bf16x8 bfr = *(const bf16x8*)(&Ubf[USWZ(c, k0)]);
                    acc2[j] = __builtin_amdgcn_mfma_f32_16x16x32_bf16(a, bfr, acc2[j], 0, 0, 0);
                }
            }
        }
        __syncthreads();

        // wave 0 catches up on its T@U; then all waves: Q@S; write Yb
        if (wv == 0) {
            #pragma unroll
            for (int ks = 0; ks < 2; ++ks) {
                const int k0 = ks * 32 + q * 8;
                const bf16x8 a = *(const bf16x8*)(&Tm[(mt * 16 + cl) * 72 + k0]);
                #pragma unroll
                for (int j = 0; j < 2; ++j) {
                    const int c = (nt0 + j) * 16 + cl;
                    const bf16x8 bfr = *(const bf16x8*)(&Ubf[USWZ(c, k0)]);
                    acc2[j] = __builtin_amdgcn_mfma_f32_16x16x32_bf16(a, bfr, acc2[j], 0, 0, 0);
                }
            }
        }
        {
            #pragma unroll
            for (int ks = 0; ks < 4; ++ks) {
                const int k0 = ks * 32 + q * 8;
                #pragma unroll
                for (int j = 0; j < 2; ++j) {
                    const int c = (nt0 + j) * 16 + cl;
                    const bf16x8 bfr = *(const bf16x8*)(&Sbf[SSWZ(c, k0)]);
                    acc2[j] = __builtin_amdgcn_mfma_f32_16x16x32_bf16(qA[ks], bfr, acc2[j], 0, 0, 0);
                }
            }
            bf16* Yb = (bf16*)Ctr;   // Ctr dead after scan
            #pragma unroll
            for (int j = 0; j < 2; ++j) {
                const int c = (nt0 + j) * 16 + cl;
                bf16x4 yv;
                #pragma unroll
                for (int r = 0; r < 4; ++r) yv[r] = (bf16)acc2[j][r];
                *(bf16x4*)(&Yb[c * 72 + mt * 16 + q * 4]) = yv;
            }
        }
        __syncthreads();

        // coalesced y store + stage prefetched u for it+1
        {
            const bf16* Yb = (const bf16*)Ctr;
            const bf16x8 v = *(const bf16x8*)(&Yb[c0 * 72 + j0]);
            *(bf16x8*)(ybf + (size_t)bh * L_ + c0 * 64 + j0) = v;
        }
        if (it < 3) {
            bf16x8 t;
            t[0] = (bf16)pf0.x; t[1] = (bf16)pf0.y; t[2] = (bf16)pf0.z; t[3] = (bf16)pf0.w;
            t[4] = (bf16)pf1.x; t[5] = (bf16)pf1.y; t[6] = (bf16)pf1.z; t[7] = (bf16)pf1.w;
            *(bf16x8*)(&Ubf[USWZ(c0, j0)]) = t;
        }
        __syncthreads();
    }
}

// ----------------------------------------------------------------- k_mlp ----
// THE r6 VARIABLE: 32-l tiles -> 2048 blocks (8/CU, LDS 9.7 KB, accs halved
// so the 64-VGPR budget at 8 waves/EU fits) for 2x inter-block phase overlap
// on the serial {stage -> MFMA -> MFMA -> store} chain. Same mapping as the
// 64-l version with nt<2; total MFMA and HBM traffic unchanged.
#define YSTR 136
__global__ __launch_bounds__(256, 8) void k_mlp(
        const bf16* __restrict__ ybf,
        const bf16* __restrict__ w1b, const bf16* __restrict__ w2b,
        const float* __restrict__ b1, const float* __restrict__ b2,
        float* __restrict__ out) {
    __shared__ bf16 YT[32 * YSTR];    // y tile transposed [l][h]; reused as H1T
    __shared__ float B1s[H_], B2s[H_];

    const int tid = threadIdx.x;
    const int b   = blockIdx.x >> 7;
    const int lt  = blockIdx.x & 127;
    const int l0  = lt * 32;

    if (tid < H_) { B1s[tid] = b1[tid]; B2s[tid] = b2[tid]; }

    // ---- stage y tile transposed [l][h]: h-pair per thread, bf16x2 writes
    {
        const int h0  = (tid & 63) * 2;          // within wave: h0 = 2*lane
        const int lh  = (tid >> 6) * 8;          // wave w covers l = 8w..8w+8
        const bf16x8 rA = *(const bf16x8*)(ybf + ((size_t)b * H_ + h0)     * L_ + l0 + lh);
        const bf16x8 rB = *(const bf16x8*)(ybf + ((size_t)b * H_ + h0 + 1) * L_ + l0 + lh);
        #pragma unroll
        for (int e = 0; e < 8; ++e) {
            *(bf16x2*)(&YT[(lh + e) * YSTR + h0]) = (bf16x2){rA[e], rB[e]};
        }
    }
    __syncthreads();

    const int lane = tid & 63;
    const int wv   = tid >> 6;
    const int m    = lane & 15;
    const int q    = lane >> 4;
    const int m0   = wv * 32;

    // ---- layer 1 ----
    f32x4 acc[2][2];
    #pragma unroll
    for (int i = 0; i < 2; ++i)
        #pragma unroll
        for (int nt = 0; nt < 2; ++nt) acc[i][nt] = (f32x4){0.f, 0.f, 0.f, 0.f};

    #pragma unroll
    for (int kb = 0; kb < 4; ++kb) {
        const bf16x8 a0 = *(const bf16x8*)(w1b + (size_t)(m0 + m)      * H_ + kb * 32 + q * 8);
        const bf16x8 a1 = *(const bf16x8*)(w1b + (size_t)(m0 + 16 + m) * H_ + kb * 32 + q * 8);
        #pragma unroll
        for (int nt = 0; nt < 2; ++nt) {
            const bf16x8 bfr = *(const bf16x8*)(&YT[(nt * 16 + m) * YSTR + kb * 32 + q * 8]);
            acc[0][nt] = __builtin_amdgcn_mfma_f32_16x16x32_bf16(a0, bfr, acc[0][nt], 0, 0, 0);
            acc[1][nt] = __builtin_amdgcn_mfma_f32_16x16x32_bf16(a1, bfr, acc[1][nt], 0, 0, 0);
        }
    }
    __syncthreads();   // all YT reads done before H1T(=YT) writes

    #pragma unroll
    for (int i = 0; i < 2; ++i) {
        const int o0 = m0 + 16 * i + 4 * q;
        #pragma unroll
        for (int nt = 0; nt < 2; ++nt) {
            const f32x4 v = acc[i][nt];
            bf16x4 hv;
            #pragma unroll
            for (int r = 0; r < 4; ++r) {
                float x = v[r] + B1s[o0 + r];
                hv[r] = (bf16)fmaxf(x, 0.f);
            }
            *(bf16x4*)(&YT[(nt * 16 + m) * YSTR + o0]) = hv;
        }
    }
    __syncthreads();

    // ---- layer 2 ----
    f32x4 acc2[2][2];
    #pragma unroll
    for (int i = 0; i < 2; ++i)
        #pragma unroll
        for (int nt = 0; nt < 2; ++nt) acc2[i][nt] = (f32x4){0.f, 0.f, 0.f, 0.f};

    #pragma unroll
    for (int kb = 0; kb < 4; ++kb) {
        const bf16x8 a0 = *(const bf16x8*)(w2b + (size_t)(m0 + m)      * H_ + kb * 32 + q * 8);
        const bf16x8 a1 = *(const bf16x8*)(w2b + (size_t)(m0 + 16 + m) * H_ + kb * 32 + q * 8);
        #pragma unroll
        for (int nt = 0; nt < 2; ++nt) {
            const bf16x8 bfr = *(const bf16x8*)(&YT[(nt * 16 + m) * YSTR + kb * 32 + q * 8]);
            acc2[0][nt] = __builtin_amdgcn_mfma_f32_16x16x32_bf16(a0, bfr, acc2[0][nt], 0, 0, 0);
            acc2[1][nt] = __builtin_amdgcn_mfma_f32_16x16x32_bf16(a1, bfr, acc2[1][nt], 0, 0, 0);
        }
    }

    // ---- epilogue: bias + relu + direct f32 stores ----
    #pragma unroll
    for (int i = 0; i < 2; ++i) {
        const int o0 = m0 + 16 * i + 4 * q;
        #pragma unroll
        for (int nt = 0; nt < 2; ++nt) {
            const f32x4 v = acc2[i][nt];
            #pragma unroll
            for (int r = 0; r < 4; ++r) {
                float x = v[r] + B2s[o0 + r];
                x = fmaxf(x, 0.f);
                out[((size_t)b * H_ + o0 + r) * L_ + l0 + nt * 16 + m] = x;
            }
        }
    }
}

// ---------------------------------------------------------------- launch ----
extern "C" void kernel_launch(void* const* d_in, const int* in_sizes, int n_in,
                              void* d_out, int out_size, void* d_ws, size_t ws_size,
                              hipStream_t stream) {
    const float* u   = (const float*)d_in[0];
    const float* lre = (const float*)d_in[1];
    const float* lim = (const float*)d_in[2];
    const float* wre = (const float*)d_in[3];
    const float* wim = (const float*)d_in[4];
    const float* dv  = (const float*)d_in[5];
    const float* w1  = (const float*)d_in[6];
    const float* b1  = (const float*)d_in[7];
    const float* w2  = (const float*)d_in[8];
    const float* b2  = (const float*)d_in[9];
    float* out = (float*)d_out;

    char* ws = (char*)d_ws;
    bf16* ybf = (bf16*)ws;   ws += (size_t)B_ * H_ * L_ * 2;   // 16.78 MB
    bf16* w1b = (bf16*)ws;   ws += H_ * H_ * 2;
    bf16* w2b = (bf16*)ws;   ws += H_ * H_ * 2;

    hipLaunchKernelGGL(k_ssm3, dim3(512), dim3(512), 0, stream,
                       u, lre, lim, wre, wim, dv, w1, w2, w1b, w2b, ybf);
    hipLaunchKernelGGL(k_mlp, dim3(B_ * (L_ / 32)), dim3(256), 0, stream,
                       ybf, w1b, w2b, b1, b2, out);
}

// Round 7
// 131.456 us; speedup vs baseline: 1.0461x; 1.0461x over previous
//
#include <hip/hip_runtime.h>
#include <hip/hip_bf16.h>

#define B_ 16
#define H_ 128
#define L_ 4096
#define N_ 64
#define DT_ 0.01f

typedef __bf16 bf16;
typedef __bf16 bf16x8 __attribute__((ext_vector_type(8)));
typedef __bf16 bf16x4 __attribute__((ext_vector_type(4)));
typedef __bf16 bf16x2 __attribute__((ext_vector_type(2)));
typedef float f32x4 __attribute__((ext_vector_type(4)));

#define USWZ(c, k) ((c) * 64 + (((((k) >> 4) ^ ((c) & 3)) << 4) | ((k) & 15)))
#define SSWZ(c, k) ((c) * 128 + (((((k) >> 4) ^ ((c) & 7)) << 4) | ((k) & 15)))

// ---------------------------------------------------------------- k_ssm3 ----
// BYTE-IDENTICAL to the r4 PASS build (session anchor; prefetch confirmed
// -2.5us vs r0). Untouched this round: r7's single variable is the k_mlp
// latency-chain rewrite. Scan-variant family abandoned (r2/r3/r5 failures).
__global__ __launch_bounds__(512, 4) void k_ssm3(
        const float* __restrict__ u,
        const float* __restrict__ lre, const float* __restrict__ lim,
        const float* __restrict__ wre, const float* __restrict__ wim,
        const float* __restrict__ dv,
        const float* __restrict__ w1, const float* __restrict__ w2,
        bf16* __restrict__ w1b, bf16* __restrict__ w2b,
        bf16* __restrict__ ybf) {
    alignas(16) __shared__ char smem[68352];
    bf16*  Ubf  = (bf16*)smem;                    //  8192 B
    float* Ctr  = (float*)(smem + 8192);          // 33280 B fp32 [row][c] stride 65 (aliased Yb)
    bf16*  Sbf  = (bf16*)(smem + 41472);          // 16384 B
    bf16*  Tm   = (bf16*)(smem + 57856);          //  9216 B
    float* lamS = (float*)(smem + 67072);         //  1024 B: [lr|li|wr|wi][64] (lr,li pre-scaled)
    float* taps = (float*)(smem + 68096);         //   256 B

    const int tid  = threadIdx.x;
    const int lane = tid & 63, wv = tid >> 6;     // wv in [0,8)
    const int cl   = lane & 15, q = lane >> 4;
    const int bId  = blockIdx.x;
    const int h    = bId & 127;
    const int bg   = bId >> 7;                    // [0,4)
    const int c0   = tid >> 3, j0 = (tid & 7) << 3;

    // ---- issue it=0 u loads FIRST: latency hides under transcendental setup
    const float4* ps0 = (const float4*)(u + (size_t)((bg * 4) * 128 + h) * L_ + c0 * 64 + j0);
    const float4 f0 = ps0[0], f1 = ps0[1];

    // ---- weight cast + lambda/W staging ----
    if (tid < 64) {
        if (bId < 256) w1b[bId * 64 + tid] = (bf16)w1[bId * 64 + tid];
        else           w2b[(bId - 256) * 64 + tid] = (bf16)w2[(bId - 256) * 64 + tid];
        lamS[tid]       = lre[h * 64 + tid] * DT_;
        lamS[64 + tid]  = lim[h * 64 + tid] * DT_;
        lamS[128 + tid] = wre[h * 64 + tid];
        lamS[192 + tid] = wim[h * 64 + tid];
    }
    __syncthreads();

    // ---- P fragments (MFMA-1 A-op) in regs: row = wv*16+cl ----
    bf16x8 pA0, pA1;
    {
        const int row = wv * 16 + cl;
        const int n = row & 63;
        const bool isIm = row >= 64;
        const float lr = lamS[n], li = lamS[64 + n];
        #pragma unroll
        for (int jj = 0; jj < 8; ++jj) {
            const float p0 = (float)(63 - (q * 8 + jj));
            const float e0 = __expf(p0 * lr);
            pA0[jj] = (bf16)(isIm ? e0 * __sinf(p0 * li) : e0 * __cosf(p0 * li));
            const float p1 = (float)(63 - (32 + q * 8 + jj));
            const float e1 = __expf(p1 * lr);
            pA1[jj] = (bf16)(isIm ? e1 * __sinf(p1 * li) : e1 * __cosf(p1 * li));
        }
    }
    // ---- Q fragments (MFMA-2 A-op) in regs: dlt = (wv>>1)*16+cl ----
    bf16x8 qA[4];
    {
        const float fd = (float)((wv >> 1) * 16 + cl + 1);   // dlt+1
        #pragma unroll
        for (int ks = 0; ks < 4; ++ks) {
            #pragma unroll
            for (int nn = 0; nn < 4; ++nn) {
                const int n = ks * 16 + q * 4 + nn;          // n = k>>1
                const float lr = lamS[n], li = lamS[64 + n];
                const float wr = lamS[128 + n], wi = lamS[192 + n];
                const float e  = __expf(fd * lr);
                const float cr = e * __cosf(fd * li), ci = e * __sinf(fd * li);
                qA[ks][2 * nn]     = (bf16)(wr * cr - wi * ci);
                qA[ks][2 * nn + 1] = (bf16)(-(wr * ci + wi * cr));
            }
        }
    }
    // ---- A^64 for the scan (lane = mode n) ----
    float a64r, a64i;
    {
        const float lr = lamS[lane], li = lamS[64 + lane];
        const float e = __expf(64.f * lr);
        a64r = e * __cosf(64.f * li);
        a64i = e * __sinf(64.f * li);
    }
    // ---- taps[dlt] = sum_n Re(W_n A_n^dlt): wave wv does dlt = wv*8+i ----
    {
        const float lr = lamS[lane], li = lamS[64 + lane];
        const float wr = lamS[128 + lane], wi = lamS[192 + lane];
        #pragma unroll
        for (int i = 0; i < 8; ++i) {
            const int dlt = wv * 8 + i;
            const float fd = (float)dlt;
            const float e = __expf(fd * lr);
            float t = wr * e * __cosf(fd * li) - wi * e * __sinf(fd * li);
            #pragma unroll
            for (int d = 1; d < 64; d <<= 1) t += __shfl_xor(t, d, 64);
            if (lane == 0) taps[dlt] = t;
        }
    }
    // ---- stage it=0 u into Ubf (loads already in flight) ----
    {
        bf16x8 t;
        t[0] = (bf16)f0.x; t[1] = (bf16)f0.y; t[2] = (bf16)f0.z; t[3] = (bf16)f0.w;
        t[4] = (bf16)f1.x; t[5] = (bf16)f1.y; t[6] = (bf16)f1.z; t[7] = (bf16)f1.w;
        *(bf16x8*)(&Ubf[USWZ(c0, j0)]) = t;
    }
    __syncthreads();

    // ---- Toeplitz Tm[dlt][j] = taps[dlt-j] (+d_h on diag) ----
    {
        const int dlt = tid >> 3, jj0 = (tid & 7) << 3;
        const float dh = dv[h];
        bf16x8 t;
        #pragma unroll
        for (int e = 0; e < 8; ++e) {
            const int j = jj0 + e;
            float v = (j <= dlt) ? taps[dlt - j] : 0.f;
            if (j == dlt) v += dh;
            t[e] = (bf16)v;
        }
        *(bf16x8*)(&Tm[dlt * 72 + jj0]) = t;
    }

    // ---- 4 batches per block ----
    const int mt = wv >> 1, nt0 = (wv & 1) * 2;
    float4 pf0 = {0.f, 0.f, 0.f, 0.f}, pf1 = {0.f, 0.f, 0.f, 0.f};
    for (int it = 0; it < 4; ++it) {
        const int bh = (bg * 4 + it) * 128 + h;

        // MFMA-1: Ctr[row][c] = P @ U (fp32), wave wv owns rows [16wv,16wv+16)
        {
            f32x4 acc[4];
            #pragma unroll
            for (int nt = 0; nt < 4; ++nt) acc[nt] = (f32x4){0.f, 0.f, 0.f, 0.f};
            #pragma unroll
            for (int nt = 0; nt < 4; ++nt) {
                const int c = nt * 16 + cl;
                const bf16x8 b0 = *(const bf16x8*)(&Ubf[USWZ(c, q * 8)]);
                acc[nt] = __builtin_amdgcn_mfma_f32_16x16x32_bf16(pA0, b0, acc[nt], 0, 0, 0);
                const bf16x8 bq = *(const bf16x8*)(&Ubf[USWZ(c, 32 + q * 8)]);
                acc[nt] = __builtin_amdgcn_mfma_f32_16x16x32_bf16(pA1, bq, acc[nt], 0, 0, 0);
            }
            #pragma unroll
            for (int nt = 0; nt < 4; ++nt)
                #pragma unroll
                for (int r = 0; r < 4; ++r)
                    Ctr[(wv * 16 + q * 4 + r) * 65 + nt * 16 + cl] = acc[nt][r];
        }
        __syncthreads();

        // issue u prefetch for it+1 here: outside MFMA-1's register-pressure
        // peak; the scan/T@U phase below hides the HBM latency
        if (it < 3) {
            const float4* ps = (const float4*)(u + (size_t)((bg * 4 + it + 1) * 128 + h) * L_
                                               + c0 * 64 + j0);
            pf0 = ps[0]; pf1 = ps[1];
        }

        // OVERLAPPED PHASE: wave 0 scans; waves 1-7 do the S-independent T@U
        f32x4 acc2[2];
        acc2[0] = (f32x4){0.f, 0.f, 0.f, 0.f};
        acc2[1] = (f32x4){0.f, 0.f, 0.f, 0.f};
        if (wv == 0) {
            float sr = 0.f, si = 0.f;
            #pragma unroll 8
            for (int c = 0; c < 64; ++c) {
                bf16* sp = &Sbf[SSWZ(c, 2 * lane)];
                sp[0] = (bf16)sr;
                sp[1] = (bf16)si;
                const float cr = Ctr[lane * 65 + c];
                const float ci = Ctr[(64 + lane) * 65 + c];
                const float nr = fmaf(a64r, sr, fmaf(-a64i, si, cr));
                const float ni = fmaf(a64r, si, fmaf(a64i, sr, ci));
                sr = nr; si = ni;
            }
        } else {
            #pragma unroll
            for (int ks = 0; ks < 2; ++ks) {
                const int k0 = ks * 32 + q * 8;
                const bf16x8 a = *(const bf16x8*)(&Tm[(mt * 16 + cl) * 72 + k0]);
                #pragma unroll
                for (int j = 0; j < 2; ++j) {
                    const int c = (nt0 + j) * 16 + cl;
                    const bf16x8 bfr = *(const bf16x8*)(&Ubf[USWZ(c, k0)]);
                    acc2[j] = __builtin_amdgcn_mfma_f32_16x16x32_bf16(a, bfr, acc2[j], 0, 0, 0);
                }
            }
        }
        __syncthreads();

        // wave 0 catches up on its T@U; then all waves: Q@S; write Yb
        if (wv == 0) {
            #pragma unroll
            for (int ks = 0; ks < 2; ++ks) {
                const int k0 = ks * 32 + q * 8;
                const bf16x8 a = *(const bf16x8*)(&Tm[(mt * 16 + cl) * 72 + k0]);
                #pragma unroll
                for (int j = 0; j < 2; ++j) {
                    const int c = (nt0 + j) * 16 + cl;
                    const bf16x8 bfr = *(const bf16x8*)(&Ubf[USWZ(c, k0)]);
                    acc2[j] = __builtin_amdgcn_mfma_f32_16x16x32_bf16(a, bfr, acc2[j], 0, 0, 0);
                }
            }
        }
        {
            #pragma unroll
            for (int ks = 0; ks < 4; ++ks) {
                const int k0 = ks * 32 + q * 8;
                #pragma unroll
                for (int j = 0; j < 2; ++j) {
                    const int c = (nt0 + j) * 16 + cl;
                    const bf16x8 bfr = *(const bf16x8*)(&Sbf[SSWZ(c, k0)]);
                    acc2[j] = __builtin_amdgcn_mfma_f32_16x16x32_bf16(qA[ks], bfr, acc2[j], 0, 0, 0);
                }
            }
            bf16* Yb = (bf16*)Ctr;   // Ctr dead after scan
            #pragma unroll
            for (int j = 0; j < 2; ++j) {
                const int c = (nt0 + j) * 16 + cl;
                bf16x4 yv;
                #pragma unroll
                for (int r = 0; r < 4; ++r) yv[r] = (bf16)acc2[j][r];
                *(bf16x4*)(&Yb[c * 72 + mt * 16 + q * 4]) = yv;
            }
        }
        __syncthreads();

        // coalesced y store + stage prefetched u for it+1
        {
            const bf16* Yb = (const bf16*)Ctr;
            const bf16x8 v = *(const bf16x8*)(&Yb[c0 * 72 + j0]);
            *(bf16x8*)(ybf + (size_t)bh * L_ + c0 * 64 + j0) = v;
        }
        if (it < 3) {
            bf16x8 t;
            t[0] = (bf16)pf0.x; t[1] = (bf16)pf0.y; t[2] = (bf16)pf0.z; t[3] = (bf16)pf0.w;
            t[4] = (bf16)pf1.x; t[5] = (bf16)pf1.y; t[6] = (bf16)pf1.z; t[7] = (bf16)pf1.w;
            *(bf16x8*)(&Ubf[USWZ(c0, j0)]) = t;
        }
        __syncthreads();
    }
}

// ----------------------------------------------------------------- k_mlp ----
// THE r7 VARIABLE: latency-chain collapse. 64-l tiles (r6's 32-l regressed:
// per-block fixed latency dominates -> fewer, fatter blocks + ILP). All global
// loads hoisted: ybf staging (4x bf16x8) + all 8 w1 fragments issued at kernel
// top, 8 w2 fragments issued right after the staging barrier (consumed only
// after the relu barrier -> ~500+ cycles of cover). Weight loads no longer
// gate the MFMA loops on L2 round-trips. launch_bounds(256,4): VGPR budget
// 128 for the ~115-reg peak; 1024 blocks still all co-resident at 4/CU.
#define YSTR 136
__global__ __launch_bounds__(256, 4) void k_mlp(
        const bf16* __restrict__ ybf,
        const bf16* __restrict__ w1b, const bf16* __restrict__ w2b,
        const float* __restrict__ b1, const float* __restrict__ b2,
        float* __restrict__ out) {
    __shared__ bf16 YT[64 * YSTR];    // y tile transposed [l][h]; reused as H1T
    __shared__ float B1s[H_], B2s[H_];

    const int tid = threadIdx.x;
    const int b   = blockIdx.x >> 6;
    const int lt  = blockIdx.x & 63;
    const int l0  = lt * 64;

    const int lane = tid & 63;
    const int wv   = tid >> 6;
    const int m    = lane & 15;
    const int q    = lane >> 4;
    const int m0   = wv * 32;

    // ---- hoisted global loads: ybf staging + w1 fragments + biases, all in
    // flight before any LDS op (one exposed HBM latency instead of a chain)
    const int h0  = (tid & 63) * 2;          // within wave: h0 = 2*lane
    const int lh  = (tid >> 6) * 16;         // wave w covers l = 16w..16w+16
    const bf16x8* s0 = (const bf16x8*)(ybf + ((size_t)b * H_ + h0)     * L_ + l0 + lh);
    const bf16x8* s1 = (const bf16x8*)(ybf + ((size_t)b * H_ + h0 + 1) * L_ + l0 + lh);
    const bf16x8 r00 = s0[0], r01 = s0[1];
    const bf16x8 r10 = s1[0], r11 = s1[1];

    bf16x8 w1f[2][4];
    #pragma unroll
    for (int i = 0; i < 2; ++i)
        #pragma unroll
        for (int kb = 0; kb < 4; ++kb)
            w1f[i][kb] = *(const bf16x8*)(w1b + (size_t)(m0 + 16 * i + m) * H_ + kb * 32 + q * 8);

    float b1v = 0.f, b2v = 0.f;
    if (tid < H_) { b1v = b1[tid]; b2v = b2[tid]; }

    // ---- stage y tile transposed [l][h]: h-pair per thread, bf16x2 writes
    {
        #pragma unroll
        for (int e = 0; e < 8; ++e) {
            *(bf16x2*)(&YT[(lh + e)     * YSTR + h0]) = (bf16x2){r00[e], r10[e]};
            *(bf16x2*)(&YT[(lh + 8 + e) * YSTR + h0]) = (bf16x2){r01[e], r11[e]};
        }
    }
    if (tid < H_) { B1s[tid] = b1v; B2s[tid] = b2v; }
    __syncthreads();

    // ---- issue w2 fragments now: consumed only after the relu barrier ----
    bf16x8 w2f[2][4];
    #pragma unroll
    for (int i = 0; i < 2; ++i)
        #pragma unroll
        for (int kb = 0; kb < 4; ++kb)
            w2f[i][kb] = *(const bf16x8*)(w2b + (size_t)(m0 + 16 * i + m) * H_ + kb * 32 + q * 8);

    // ---- layer 1 (weights already in registers) ----
    f32x4 acc[2][4];
    #pragma unroll
    for (int i = 0; i < 2; ++i)
        #pragma unroll
        for (int nt = 0; nt < 4; ++nt) acc[i][nt] = (f32x4){0.f, 0.f, 0.f, 0.f};

    #pragma unroll
    for (int kb = 0; kb < 4; ++kb) {
        #pragma unroll
        for (int nt = 0; nt < 4; ++nt) {
            const bf16x8 bfr = *(const bf16x8*)(&YT[(nt * 16 + m) * YSTR + kb * 32 + q * 8]);
            acc[0][nt] = __builtin_amdgcn_mfma_f32_16x16x32_bf16(w1f[0][kb], bfr, acc[0][nt], 0, 0, 0);
            acc[1][nt] = __builtin_amdgcn_mfma_f32_16x16x32_bf16(w1f[1][kb], bfr, acc[1][nt], 0, 0, 0);
        }
    }
    __syncthreads();   // all YT reads done before H1T(=YT) writes

    #pragma unroll
    for (int i = 0; i < 2; ++i) {
        const int o0 = m0 + 16 * i + 4 * q;
        #pragma unroll
        for (int nt = 0; nt < 4; ++nt) {
            const f32x4 v = acc[i][nt];
            bf16x4 hv;
            #pragma unroll
            for (int r = 0; r < 4; ++r) {
                float x = v[r] + B1s[o0 + r];
                hv[r] = (bf16)fmaxf(x, 0.f);
            }
            *(bf16x4*)(&YT[(nt * 16 + m) * YSTR + o0]) = hv;
        }
    }
    __syncthreads();

    // ---- layer 2 (weights already in registers) ----
    f32x4 acc2[2][4];
    #pragma unroll
    for (int i = 0; i < 2; ++i)
        #pragma unroll
        for (int nt = 0; nt < 4; ++nt) acc2[i][nt] = (f32x4){0.f, 0.f, 0.f, 0.f};

    #pragma unroll
    for (int kb = 0; kb < 4; ++kb) {
        #pragma unroll
        for (int nt = 0; nt < 4; ++nt) {
            const bf16x8 bfr = *(const bf16x8*)(&YT[(nt * 16 + m) * YSTR + kb * 32 + q * 8]);
            acc2[0][nt] = __builtin_amdgcn_mfma_f32_16x16x32_bf16(w2f[0][kb], bfr, acc2[0][nt], 0, 0, 0);
            acc2[1][nt] = __builtin_amdgcn_mfma_f32_16x16x32_bf16(w2f[1][kb], bfr, acc2[1][nt], 0, 0, 0);
        }
    }

    // ---- epilogue: bias + relu + direct f32 stores ----
    #pragma unroll
    for (int i = 0; i < 2; ++i) {
        const int o0 = m0 + 16 * i + 4 * q;
        #pragma unroll
        for (int nt = 0; nt < 4; ++nt) {
            const f32x4 v = acc2[i][nt];
            #pragma unroll
            for (int r = 0; r < 4; ++r) {
                float x = v[r] + B2s[o0 + r];
                x = fmaxf(x, 0.f);
                out[((size_t)b * H_ + o0 + r) * L_ + l0 + nt * 16 + m] = x;
            }
        }
    }
}

// ---------------------------------------------------------------- launch ----
extern "C" void kernel_launch(void* const* d_in, const int* in_sizes, int n_in,
                              void* d_out, int out_size, void* d_ws, size_t ws_size,
                              hipStream_t stream) {
    const float* u   = (const float*)d_in[0];
    const float* lre = (const float*)d_in[1];
    const float* lim = (const float*)d_in[2];
    const float* wre = (const float*)d_in[3];
    const float* wim = (const float*)d_in[4];
    const float* dv  = (const float*)d_in[5];
    const float* w1  = (const float*)d_in[6];
    const float* b1  = (const float*)d_in[7];
    const float* w2  = (const float*)d_in[8];
    const float* b2  = (const float*)d_in[9];
    float* out = (float*)d_out;

    char* ws = (char*)d_ws;
    bf16* ybf = (bf16*)ws;   ws += (size_t)B_ * H_ * L_ * 2;   // 16.78 MB
    bf16* w1b = (bf16*)ws;   ws += H_ * H_ * 2;
    bf16* w2b = (bf16*)ws;   ws += H_ * H_ * 2;

    hipLaunchKernelGGL(k_ssm3, dim3(512), dim3(512), 0, stream,
                       u, lre, lim, wre, wim, dv, w1, w2, w1b, w2b, ybf);
    hipLaunchKernelGGL(k_mlp, dim3(B_ * (L_ / 64)), dim3(256), 0, stream,
                       ybf, w1b, w2b, b1, b2, out);
}

// Round 8
// 129.906 us; speedup vs baseline: 1.0586x; 1.0119x over previous
//
#include <hip/hip_runtime.h>
#include <hip/hip_bf16.h>

#define B_ 16
#define H_ 128
#define L_ 4096
#define N_ 64
#define DT_ 0.01f

typedef __bf16 bf16;
typedef __bf16 bf16x8 __attribute__((ext_vector_type(8)));
typedef __bf16 bf16x4 __attribute__((ext_vector_type(4)));
typedef __bf16 bf16x2 __attribute__((ext_vector_type(2)));
typedef float f32x4 __attribute__((ext_vector_type(4)));

#define USWZ(c, k) ((c) * 64 + (((((k) >> 4) ^ ((c) & 3)) << 4) | ((k) & 15)))
#define SSWZ(c, k) ((c) * 128 + (((((k) >> 4) ^ ((c) & 7)) << 4) | ((k) & 15)))

// ------------------------------------------------------------------ scan ----
// r4's scan loop, byte-identical math, hoisted into a forceinline helper with
// __restrict__ params. On inlining, clang emits scoped-noalias metadata for
// restrict parameters -> the scheduler may hoist step c+1's Ctr loads above
// step c's Sbf stores (illegal before: both pointers derive from one smem
// array, so conservative aliasing forced store->wait->load->wait per step,
// ~2 LDS round-trips/step = the bulk of k_ssm3's 26k cycles/iteration).
// Promise is true in-scope: during the scan, Ctr is only read via Cr and Sbf
// only written via Sw (the Yb=Ctr alias lives outside this scope, after a
// barrier). Loads are placed before the stores in the body -- semantically
// identical (stores write the pre-update state either way).
__device__ __forceinline__ void scan64(const float* __restrict__ Cr,
                                       bf16* __restrict__ Sw,
                                       const int lane,
                                       const float a64r, const float a64i) {
    float sr = 0.f, si = 0.f;
    #pragma unroll 8
    for (int c = 0; c < 64; ++c) {
        const float cr = Cr[lane * 65 + c];
        const float ci = Cr[(64 + lane) * 65 + c];
        bf16* sp = &Sw[SSWZ(c, 2 * lane)];
        sp[0] = (bf16)sr;
        sp[1] = (bf16)si;
        const float nr = fmaf(a64r, sr, fmaf(-a64i, si, cr));
        const float ni = fmaf(a64r, si, fmaf(a64i, sr, ci));
        sr = nr; si = ni;
    }
}

// ---------------------------------------------------------------- k_ssm3 ----
// r4 PASS build (session anchor), single change: wave-0 scan routed through
// scan64() (restrict-scoped noalias). Everything else byte-identical.
__global__ __launch_bounds__(512, 4) void k_ssm3(
        const float* __restrict__ u,
        const float* __restrict__ lre, const float* __restrict__ lim,
        const float* __restrict__ wre, const float* __restrict__ wim,
        const float* __restrict__ dv,
        const float* __restrict__ w1, const float* __restrict__ w2,
        bf16* __restrict__ w1b, bf16* __restrict__ w2b,
        bf16* __restrict__ ybf) {
    alignas(16) __shared__ char smem[68352];
    bf16*  Ubf  = (bf16*)smem;                    //  8192 B
    float* Ctr  = (float*)(smem + 8192);          // 33280 B fp32 [row][c] stride 65 (aliased Yb)
    bf16*  Sbf  = (bf16*)(smem + 41472);          // 16384 B
    bf16*  Tm   = (bf16*)(smem + 57856);          //  9216 B
    float* lamS = (float*)(smem + 67072);         //  1024 B: [lr|li|wr|wi][64] (lr,li pre-scaled)
    float* taps = (float*)(smem + 68096);         //   256 B

    const int tid  = threadIdx.x;
    const int lane = tid & 63, wv = tid >> 6;     // wv in [0,8)
    const int cl   = lane & 15, q = lane >> 4;
    const int bId  = blockIdx.x;
    const int h    = bId & 127;
    const int bg   = bId >> 7;                    // [0,4)
    const int c0   = tid >> 3, j0 = (tid & 7) << 3;

    // ---- issue it=0 u loads FIRST: latency hides under transcendental setup
    const float4* ps0 = (const float4*)(u + (size_t)((bg * 4) * 128 + h) * L_ + c0 * 64 + j0);
    const float4 f0 = ps0[0], f1 = ps0[1];

    // ---- weight cast + lambda/W staging ----
    if (tid < 64) {
        if (bId < 256) w1b[bId * 64 + tid] = (bf16)w1[bId * 64 + tid];
        else           w2b[(bId - 256) * 64 + tid] = (bf16)w2[(bId - 256) * 64 + tid];
        lamS[tid]       = lre[h * 64 + tid] * DT_;
        lamS[64 + tid]  = lim[h * 64 + tid] * DT_;
        lamS[128 + tid] = wre[h * 64 + tid];
        lamS[192 + tid] = wim[h * 64 + tid];
    }
    __syncthreads();

    // ---- P fragments (MFMA-1 A-op) in regs: row = wv*16+cl ----
    bf16x8 pA0, pA1;
    {
        const int row = wv * 16 + cl;
        const int n = row & 63;
        const bool isIm = row >= 64;
        const float lr = lamS[n], li = lamS[64 + n];
        #pragma unroll
        for (int jj = 0; jj < 8; ++jj) {
            const float p0 = (float)(63 - (q * 8 + jj));
            const float e0 = __expf(p0 * lr);
            pA0[jj] = (bf16)(isIm ? e0 * __sinf(p0 * li) : e0 * __cosf(p0 * li));
            const float p1 = (float)(63 - (32 + q * 8 + jj));
            const float e1 = __expf(p1 * lr);
            pA1[jj] = (bf16)(isIm ? e1 * __sinf(p1 * li) : e1 * __cosf(p1 * li));
        }
    }
    // ---- Q fragments (MFMA-2 A-op) in regs: dlt = (wv>>1)*16+cl ----
    bf16x8 qA[4];
    {
        const float fd = (float)((wv >> 1) * 16 + cl + 1);   // dlt+1
        #pragma unroll
        for (int ks = 0; ks < 4; ++ks) {
            #pragma unroll
            for (int nn = 0; nn < 4; ++nn) {
                const int n = ks * 16 + q * 4 + nn;          // n = k>>1
                const float lr = lamS[n], li = lamS[64 + n];
                const float wr = lamS[128 + n], wi = lamS[192 + n];
                const float e  = __expf(fd * lr);
                const float cr = e * __cosf(fd * li), ci = e * __sinf(fd * li);
                qA[ks][2 * nn]     = (bf16)(wr * cr - wi * ci);
                qA[ks][2 * nn + 1] = (bf16)(-(wr * ci + wi * cr));
            }
        }
    }
    // ---- A^64 for the scan (lane = mode n) ----
    float a64r, a64i;
    {
        const float lr = lamS[lane], li = lamS[64 + lane];
        const float e = __expf(64.f * lr);
        a64r = e * __cosf(64.f * li);
        a64i = e * __sinf(64.f * li);
    }
    // ---- taps[dlt] = sum_n Re(W_n A_n^dlt): wave wv does dlt = wv*8+i ----
    {
        const float lr = lamS[lane], li = lamS[64 + lane];
        const float wr = lamS[128 + lane], wi = lamS[192 + lane];
        #pragma unroll
        for (int i = 0; i < 8; ++i) {
            const int dlt = wv * 8 + i;
            const float fd = (float)dlt;
            const float e = __expf(fd * lr);
            float t = wr * e * __cosf(fd * li) - wi * e * __sinf(fd * li);
            #pragma unroll
            for (int d = 1; d < 64; d <<= 1) t += __shfl_xor(t, d, 64);
            if (lane == 0) taps[dlt] = t;
        }
    }
    // ---- stage it=0 u into Ubf (loads already in flight) ----
    {
        bf16x8 t;
        t[0] = (bf16)f0.x; t[1] = (bf16)f0.y; t[2] = (bf16)f0.z; t[3] = (bf16)f0.w;
        t[4] = (bf16)f1.x; t[5] = (bf16)f1.y; t[6] = (bf16)f1.z; t[7] = (bf16)f1.w;
        *(bf16x8*)(&Ubf[USWZ(c0, j0)]) = t;
    }
    __syncthreads();

    // ---- Toeplitz Tm[dlt][j] = taps[dlt-j] (+d_h on diag) ----
    {
        const int dlt = tid >> 3, jj0 = (tid & 7) << 3;
        const float dh = dv[h];
        bf16x8 t;
        #pragma unroll
        for (int e = 0; e < 8; ++e) {
            const int j = jj0 + e;
            float v = (j <= dlt) ? taps[dlt - j] : 0.f;
            if (j == dlt) v += dh;
            t[e] = (bf16)v;
        }
        *(bf16x8*)(&Tm[dlt * 72 + jj0]) = t;
    }

    // ---- 4 batches per block ----
    const int mt = wv >> 1, nt0 = (wv & 1) * 2;
    float4 pf0 = {0.f, 0.f, 0.f, 0.f}, pf1 = {0.f, 0.f, 0.f, 0.f};
    for (int it = 0; it < 4; ++it) {
        const int bh = (bg * 4 + it) * 128 + h;

        // MFMA-1: Ctr[row][c] = P @ U (fp32), wave wv owns rows [16wv,16wv+16)
        {
            f32x4 acc[4];
            #pragma unroll
            for (int nt = 0; nt < 4; ++nt) acc[nt] = (f32x4){0.f, 0.f, 0.f, 0.f};
            #pragma unroll
            for (int nt = 0; nt < 4; ++nt) {
                const int c = nt * 16 + cl;
                const bf16x8 b0 = *(const bf16x8*)(&Ubf[USWZ(c, q * 8)]);
                acc[nt] = __builtin_amdgcn_mfma_f32_16x16x32_bf16(pA0, b0, acc[nt], 0, 0, 0);
                const bf16x8 bq = *(const bf16x8*)(&Ubf[USWZ(c, 32 + q * 8)]);
                acc[nt] = __builtin_amdgcn_mfma_f32_16x16x32_bf16(pA1, bq, acc[nt], 0, 0, 0);
            }
            #pragma unroll
            for (int nt = 0; nt < 4; ++nt)
                #pragma unroll
                for (int r = 0; r < 4; ++r)
                    Ctr[(wv * 16 + q * 4 + r) * 65 + nt * 16 + cl] = acc[nt][r];
        }
        __syncthreads();

        // issue u prefetch for it+1 here: outside MFMA-1's register-pressure
        // peak; the scan/T@U phase below hides the HBM latency
        if (it < 3) {
            const float4* ps = (const float4*)(u + (size_t)((bg * 4 + it + 1) * 128 + h) * L_
                                               + c0 * 64 + j0);
            pf0 = ps[0]; pf1 = ps[1];
        }

        // OVERLAPPED PHASE: wave 0 scans (restrict-scoped helper); waves 1-7
        // do the S-independent T@U MFMAs.
        f32x4 acc2[2];
        acc2[0] = (f32x4){0.f, 0.f, 0.f, 0.f};
        acc2[1] = (f32x4){0.f, 0.f, 0.f, 0.f};
        if (wv == 0) {
            scan64(Ctr, Sbf, lane, a64r, a64i);
        } else {
            #pragma unroll
            for (int ks = 0; ks < 2; ++ks) {
                const int k0 = ks * 32 + q * 8;
                const bf16x8 a = *(const bf16x8*)(&Tm[(mt * 16 + cl) * 72 + k0]);
                #pragma unroll
                for (int j = 0; j < 2; ++j) {
                    const int c = (nt0 + j) * 16 + cl;
                    const bf16x8 bfr = *(const bf16x8*)(&Ubf[USWZ(c, k0)]);
                    acc2[j] = __builtin_amdgcn_mfma_f32_16x16x32_bf16(a, bfr, acc2[j], 0, 0, 0);
                }
            }
        }
        __syncthreads();

        // wave 0 catches up on its T@U; then all waves: Q@S; write Yb
        if (wv == 0) {
            #pragma unroll
            for (int ks = 0; ks < 2; ++ks) {
                const int k0 = ks * 32 + q * 8;
                const bf16x8 a = *(const bf16x8*)(&Tm[(mt * 16 + cl) * 72 + k0]);
                #pragma unroll
                for (int j = 0; j < 2; ++j) {
                    const int c = (nt0 + j) * 16 + cl;
                    const bf16x8 bfr = *(const bf16x8*)(&Ubf[USWZ(c, k0)]);
                    acc2[j] = __builtin_amdgcn_mfma_f32_16x16x32_bf16(a, bfr, acc2[j], 0, 0, 0);
                }
            }
        }
        {
            #pragma unroll
            for (int ks = 0; ks < 4; ++ks) {
                const int k0 = ks * 32 + q * 8;
                #pragma unroll
                for (int j = 0; j < 2; ++j) {
                    const int c = (nt0 + j) * 16 + cl;
                    const bf16x8 bfr = *(const bf16x8*)(&Sbf[SSWZ(c, k0)]);
                    acc2[j] = __builtin_amdgcn_mfma_f32_16x16x32_bf16(qA[ks], bfr, acc2[j], 0, 0, 0);
                }
            }
            bf16* Yb = (bf16*)Ctr;   // Ctr dead after scan
            #pragma unroll
            for (int j = 0; j < 2; ++j) {
                const int c = (nt0 + j) * 16 + cl;
                bf16x4 yv;
                #pragma unroll
                for (int r = 0; r < 4; ++r) yv[r] = (bf16)acc2[j][r];
                *(bf16x4*)(&Yb[c * 72 + mt * 16 + q * 4]) = yv;
            }
        }
        __syncthreads();

        // coalesced y store + stage prefetched u for it+1
        {
            const bf16* Yb = (const bf16*)Ctr;
            const bf16x8 v = *(const bf16x8*)(&Yb[c0 * 72 + j0]);
            *(bf16x8*)(ybf + (size_t)bh * L_ + c0 * 64 + j0) = v;
        }
        if (it < 3) {
            bf16x8 t;
            t[0] = (bf16)pf0.x; t[1] = (bf16)pf0.y; t[2] = (bf16)pf0.z; t[3] = (bf16)pf0.w;
            t[4] = (bf16)pf1.x; t[5] = (bf16)pf1.y; t[6] = (bf16)pf1.z; t[7] = (bf16)pf1.w;
            *(bf16x8*)(&Ubf[USWZ(c0, j0)]) = t;
        }
        __syncthreads();
    }
}

// ----------------------------------------------------------------- k_mlp ----
// r4's PASS version verbatim (r7's hoist rewrite was a null; reverted). Slim
// LDS (YT only, 18.4 KB) -> 6 blocks/CU; bf16x2 transpose staging.
#define YSTR 136
__global__ __launch_bounds__(256, 6) void k_mlp(
        const bf16* __restrict__ ybf,
        const bf16* __restrict__ w1b, const bf16* __restrict__ w2b,
        const float* __restrict__ b1, const float* __restrict__ b2,
        float* __restrict__ out) {
    __shared__ bf16 YT[64 * YSTR];    // y tile transposed [l][h]; reused as H1T
    __shared__ float B1s[H_], B2s[H_];

    const int tid = threadIdx.x;
    const int b   = blockIdx.x >> 6;
    const int lt  = blockIdx.x & 63;
    const int l0  = lt * 64;

    if (tid < H_) { B1s[tid] = b1[tid]; B2s[tid] = b2[tid]; }

    // ---- stage y tile transposed [l][h]: h-pair per thread, bf16x2 writes
    {
        const int h0  = (tid & 63) * 2;          // within wave: h0 = 2*lane
        const int lh  = (tid >> 6) * 16;         // wave w covers l = 16w..16w+16
        const bf16x8* s0 = (const bf16x8*)(ybf + ((size_t)b * H_ + h0)     * L_ + l0 + lh);
        const bf16x8* s1 = (const bf16x8*)(ybf + ((size_t)b * H_ + h0 + 1) * L_ + l0 + lh);
        const bf16x8 r00 = s0[0], r01 = s0[1];
        const bf16x8 r10 = s1[0], r11 = s1[1];
        #pragma unroll
        for (int e = 0; e < 8; ++e) {
            *(bf16x2*)(&YT[(lh + e)     * YSTR + h0]) = (bf16x2){r00[e], r10[e]};
            *(bf16x2*)(&YT[(lh + 8 + e) * YSTR + h0]) = (bf16x2){r01[e], r11[e]};
        }
    }
    __syncthreads();

    const int lane = tid & 63;
    const int wv   = tid >> 6;
    const int m    = lane & 15;
    const int q    = lane >> 4;
    const int m0   = wv * 32;

    // ---- layer 1 ----
    f32x4 acc[2][4];
    #pragma unroll
    for (int i = 0; i < 2; ++i)
        #pragma unroll
        for (int nt = 0; nt < 4; ++nt) acc[i][nt] = (f32x4){0.f, 0.f, 0.f, 0.f};

    #pragma unroll
    for (int kb = 0; kb < 4; ++kb) {
        const bf16x8 a0 = *(const bf16x8*)(w1b + (size_t)(m0 + m)      * H_ + kb * 32 + q * 8);
        const bf16x8 a1 = *(const bf16x8*)(w1b + (size_t)(m0 + 16 + m) * H_ + kb * 32 + q * 8);
        #pragma unroll
        for (int nt = 0; nt < 4; ++nt) {
            const bf16x8 bfr = *(const bf16x8*)(&YT[(nt * 16 + m) * YSTR + kb * 32 + q * 8]);
            acc[0][nt] = __builtin_amdgcn_mfma_f32_16x16x32_bf16(a0, bfr, acc[0][nt], 0, 0, 0);
            acc[1][nt] = __builtin_amdgcn_mfma_f32_16x16x32_bf16(a1, bfr, acc[1][nt], 0, 0, 0);
        }
    }
    __syncthreads();   // all YT reads done before H1T(=YT) writes

    #pragma unroll
    for (int i = 0; i < 2; ++i) {
        const int o0 = m0 + 16 * i + 4 * q;
        #pragma unroll
        for (int nt = 0; nt < 4; ++nt) {
            const f32x4 v = acc[i][nt];
            bf16x4 hv;
            #pragma unroll
            for (int r = 0; r < 4; ++r) {
                float x = v[r] + B1s[o0 + r];
                hv[r] = (bf16)fmaxf(x, 0.f);
            }
            *(bf16x4*)(&YT[(nt * 16 + m) * YSTR + o0]) = hv;
        }
    }
    __syncthreads();

    // ---- layer 2 ----
    f32x4 acc2[2][4];
    #pragma unroll
    for (int i = 0; i < 2; ++i)
        #pragma unroll
        for (int nt = 0; nt < 4; ++nt) acc2[i][nt] = (f32x4){0.f, 0.f, 0.f, 0.f};

    #pragma unroll
    for (int kb = 0; kb < 4; ++kb) {
        const bf16x8 a0 = *(const bf16x8*)(w2b + (size_t)(m0 + m)      * H_ + kb * 32 + q * 8);
        const bf16x8 a1 = *(const bf16x8*)(w2b + (size_t)(m0 + 16 + m) * H_ + kb * 32 + q * 8);
        #pragma unroll
        for (int nt = 0; nt < 4; ++nt) {
            const bf16x8 bfr = *(const bf16x8*)(&YT[(nt * 16 + m) * YSTR + kb * 32 + q * 8]);
            acc2[0][nt] = __builtin_amdgcn_mfma_f32_16x16x32_bf16(a0, bfr, acc2[0][nt], 0, 0, 0);
            acc2[1][nt] = __builtin_amdgcn_mfma_f32_16x16x32_bf16(a1, bfr, acc2[1][nt], 0, 0, 0);
        }
    }

    // ---- epilogue: bias + relu + direct f32 stores ----
    #pragma unroll
    for (int i = 0; i < 2; ++i) {
        const int o0 = m0 + 16 * i + 4 * q;
        #pragma unroll
        for (int nt = 0; nt < 4; ++nt) {
            const f32x4 v = acc2[i][nt];
            #pragma unroll
            for (int r = 0; r < 4; ++r) {
                float x = v[r] + B2s[o0 + r];
                x = fmaxf(x, 0.f);
                out[((size_t)b * H_ + o0 + r) * L_ + l0 + nt * 16 + m] = x;
            }
        }
    }
}

// ---------------------------------------------------------------- launch ----
extern "C" void kernel_launch(void* const* d_in, const int* in_sizes, int n_in,
                              void* d_out, int out_size, void* d_ws, size_t ws_size,
                              hipStream_t stream) {
    const float* u   = (const float*)d_in[0];
    const float* lre = (const float*)d_in[1];
    const float* lim = (const float*)d_in[2];
    const float* wre = (const float*)d_in[3];
    const float* wim = (const float*)d_in[4];
    const float* dv  = (const float*)d_in[5];
    const float* w1  = (const float*)d_in[6];
    const float* b1  = (const float*)d_in[7];
    const float* w2  = (const float*)d_in[8];
    const float* b2  = (const float*)d_in[9];
    float* out = (float*)d_out;

    char* ws = (char*)d_ws;
    bf16* ybf = (bf16*)ws;   ws += (size_t)B_ * H_ * L_ * 2;   // 16.78 MB
    bf16* w1b = (bf16*)ws;   ws += H_ * H_ * 2;
    bf16* w2b = (bf16*)ws;   ws += H_ * H_ * 2;

    hipLaunchKernelGGL(k_ssm3, dim3(512), dim3(512), 0, stream,
                       u, lre, lim, wre, wim, dv, w1, w2, w1b, w2b, ybf);
    hipLaunchKernelGGL(k_mlp, dim3(B_ * (L_ / 64)), dim3(256), 0, stream,
                       ybf, w1b, w2b, b1, b2, out);
}